// Round 14
// baseline (61.807 us; speedup 1.0000x reference)
//
#include <hip/hip_runtime.h>
#include <cstddef>

constexpr int CB  = 2;
constexpr int CH  = 16;
constexpr int CS  = 4096;
constexpr int CD  = 64;
constexpr int CG  = 64;
constexpr int CBH = CB * CH;
constexpr int NS1 = 8;            // part-1 splits per bh (4 q-windows of 128)
constexpr int NS2 = 8;            // part-2 splits per bh (4 key-windows of 128)
constexpr int NPART = 64;         // contract: part = key_window*2 + key-half

typedef float  f32x16 __attribute__((ext_vector_type(16)));
typedef short  short8 __attribute__((ext_vector_type(8)));
typedef float  fvec4  __attribute__((ext_vector_type(4)));

union U8 { unsigned u[4]; short8 s; };

__device__ __forceinline__ unsigned short f2bf(float x) {
  unsigned u = __float_as_uint(x);
  unsigned r = u + 0x7fffu + ((u >> 16) & 1u);  // RNE
  return (unsigned short)(r >> 16);
}
__device__ __forceinline__ unsigned pk2(float lo, float hi) {
  return (unsigned)f2bf(lo) | ((unsigned)f2bf(hi) << 16);
}
__device__ __forceinline__ f32x16 zero16() {
  f32x16 z;
#pragma unroll
  for (int i = 0; i < 16; ++i) z[i] = 0.f;
  return z;
}

// P -> MFMA-A fragment relayout for one 16-key slot (exchange across lane^32).
#define MK_PA(dst, hi_, a0,a1,a2,a3,a4,a5,a6,a7)                         \
  {                                                                      \
    unsigned x0 = pk2(a0, a1), x1 = pk2(a2, a3);                         \
    unsigned y0 = pk2(a4, a5), y1 = pk2(a6, a7);                         \
    unsigned t0 = (unsigned)__shfl_xor((int)((hi_) ? x0 : y0), 32);      \
    if (hi_) x0 = t0; else y0 = t0;                                      \
    unsigned t1 = (unsigned)__shfl_xor((int)((hi_) ? x1 : y1), 32);      \
    if (hi_) x1 = t1; else y1 = t1;                                      \
    U8 w_; w_.u[0] = x0; w_.u[1] = x1; w_.u[2] = y0; w_.u[3] = y1;       \
    dst = w_.s;                                                          \
  }

// ---- f32 LDS tile addressing: 64 rows x 256B, 16B-slot XOR swizzle ----
__device__ __forceinline__ unsigned swz(int row, int slot) {
  return (unsigned)(row * 256 + ((slot ^ (row & 15)) << 4));
}
__device__ __forceinline__ short8 kfrag(const char* tile, int r, int s, int hi) {
  const int slot0 = 4 * s + 2 * hi;
  fvec4 a = *(const fvec4*)(tile + swz(r, slot0));
  fvec4 b = *(const fvec4*)(tile + swz(r, slot0 + 1));
  U8 w;
  w.u[0] = pk2(a[0], a[1]); w.u[1] = pk2(a[2], a[3]);
  w.u[2] = pk2(b[0], b[1]); w.u[3] = pk2(b[2], b[3]);
  return w.s;
}
__device__ __forceinline__ short8 vfrag(const char* tile, int col, int s, int hi) {
  const int sl = col >> 2, wi = (col & 3) << 2;
  float f[8];
#pragma unroll
  for (int j = 0; j < 8; ++j) {
    const int key = 16 * s + 8 * hi + j;
    f[j] = *(const float*)(tile + swz(key, sl) + wi);
  }
  U8 w;
  w.u[0] = pk2(f[0], f[1]); w.u[1] = pk2(f[2], f[3]);
  w.u[2] = pk2(f[4], f[5]); w.u[3] = pk2(f[6], f[7]);
  return w.s;
}
__device__ __forceinline__ void stage_quarter(char* tile, int row, int qtr,
                                              const float* srcrow) {
#pragma unroll
  for (int i = 0; i < 4; ++i) {
    fvec4 x = *(const fvec4*)(srcrow + qtr * 16 + i * 4);
    *(fvec4*)(tile + swz(row, qtr * 4 + i)) = x;
  }
}
__device__ __forceinline__ void stage_stream(char* tile0, char* tile1,
                                             const float* src, int tt) {
#pragma unroll
  for (int i = 0; i < 16; ++i) {
    const unsigned byte = (unsigned)(i * 2048 + tt * 16);
    fvec4 x = *(const fvec4*)((const char*)src + byte);
    const int grow = byte >> 8;          // 0..127
    const int slot = (byte >> 4) & 15;
    char* tl = (grow < 64) ? tile0 : tile1;
    *(fvec4*)(tl + swz(grow & 63, slot)) = x;
  }
}

// ---------------------------------------------------------------------------
__global__ void k_setup(const int* __restrict__ mask,
                        int* __restrict__ gpos, int* __restrict__ gcount) {
  const int b = blockIdx.x;
  const int t = threadIdx.x;  // 64
  __shared__ int cnt[64];
  if (t < CG) gpos[b * CG + t] = 0;
  const int span = CS / 64;
  const int base = b * CS + t * span;
  int c = 0;
  for (int i = 0; i < span; ++i) c += (mask[base + i] > 0) ? 1 : 0;
  cnt[t] = c;
  __syncthreads();
  int pre = 0;
  for (int j = 0; j < t; ++j) pre += cnt[j];
  for (int i = 0; i < span; ++i) {
    if (mask[base + i] > 0) {
      if (pre < CG) gpos[b * CG + pre] = t * span + i;
      ++pre;
    }
  }
  if (t == 63) gcount[b] = (pre < CG) ? pre : CG;
}

// ---------------------------------------------------------------------------
struct __align__(16) SP1 {
  float kf[64 * 64];
  float vf[64 * 64];
  float pscr[4 * 32 * 64];
};
struct __align__(16) SP2 {
  float kf[2][64 * 64];
  float vf[2][64 * 64];
};
union __align__(16) SMem { SP1 p1; SP2 p2; };

__global__ __launch_bounds__(256, 2) void k_main(
    const float* __restrict__ q, const float* __restrict__ k,
    const float* __restrict__ v,
    const int* __restrict__ gpos, const int* __restrict__ gcount,
    float* __restrict__ ctx, float* __restrict__ probs,
    float* __restrict__ pm, float* __restrict__ pl,
    unsigned short* __restrict__ pctx) {
  __shared__ SMem sm;
  const int bh = blockIdx.y, b = bh / CH, t = threadIdx.x;
  const int lane = t & 63, wv = t >> 6;
  const int hi = lane >> 5, ql = lane & 31;
  const bool isP1 = (blockIdx.x < NS1);

  if (isP1) {
    // ============================ part 1 =================================
    const int bx1 = blockIdx.x;
    const int gc = gcount[b];
    {
      const int row = t >> 2, qtr = t & 3;
      const int grow = gpos[b * CG + row];
      stage_quarter((char*)sm.p1.kf, row, qtr,
                    k + (size_t)(bh * CS + grow) * CD);
      stage_quarter((char*)sm.p1.vf, row, qtr,
                    v + (size_t)(bh * CS + grow) * CD);
    }
    __syncthreads();
    const char* bK = (const char*)sm.p1.kf;
    const char* bV = (const char*)sm.p1.vf;
    char* ps = (char*)(sm.p1.pscr + wv * 32 * 64);

#pragma unroll
    for (int it = 0; it < 4; ++it) {
      const int qbase = (bx1 * 4 + it) * 128;
      const int qrow = qbase + wv * 32 + ql;
      const float* qr = q + ((size_t)(bh * CS + qrow)) * CD + hi * 8;
      fvec4 qa[8];
#pragma unroll
      for (int s = 0; s < 4; ++s) {
        qa[2 * s]     = *(const fvec4*)(qr + s * 16);
        qa[2 * s + 1] = *(const fvec4*)(qr + s * 16 + 4);
      }
      short8 qf[4];
#pragma unroll
      for (int s = 0; s < 4; ++s) {
        U8 w;
        w.u[0] = pk2(qa[2 * s][0] * 0.125f, qa[2 * s][1] * 0.125f);
        w.u[1] = pk2(qa[2 * s][2] * 0.125f, qa[2 * s][3] * 0.125f);
        w.u[2] = pk2(qa[2 * s + 1][0] * 0.125f, qa[2 * s + 1][1] * 0.125f);
        w.u[3] = pk2(qa[2 * s + 1][2] * 0.125f, qa[2 * s + 1][3] * 0.125f);
        qf[s] = w.s;
      }

      f32x16 acc0 = zero16(), acc1 = zero16();
#pragma unroll
      for (int s = 0; s < 4; ++s) {
        acc0 = __builtin_amdgcn_mfma_f32_32x32x16_bf16(
            kfrag(bK, ql, s, hi), qf[s], acc0, 0, 0, 0);
        acc1 = __builtin_amdgcn_mfma_f32_32x32x16_bf16(
            kfrag(bK, 32 + ql, s, hi), qf[s], acc1, 0, 0, 0);
      }

      float e0[16], e1[16];
      float m = -1e30f;
#pragma unroll
      for (int r = 0; r < 16; ++r) {
        const int key0 = (r & 3) + 8 * (r >> 2) + 4 * hi;
        float x0 = (key0 < gc) ? acc0[r] : -1e30f;
        float x1 = (key0 + 32 < gc) ? acc1[r] : -1e30f;
        e0[r] = x0; e1[r] = x1;
        m = fmaxf(m, fmaxf(x0, x1));
      }
      m = fmaxf(m, __shfl_xor(m, 32));
      float ls = 0.f;
#pragma unroll
      for (int r = 0; r < 16; ++r) {
        e0[r] = __expf(e0[r] - m); ls += e0[r];
        e1[r] = __expf(e1[r] - m); ls += e1[r];
      }
      ls += __shfl_xor(ls, 32);
      const float inv = 1.0f / ls;
#pragma unroll
      for (int r = 0; r < 16; ++r) { e0[r] *= inv; e1[r] *= inv; }

      // probs: per-wave LDS bounce, nontemporal coalesced stream-out
#pragma unroll
      for (int g4 = 0; g4 < 4; ++g4) {
        fvec4 o0 = {e0[4 * g4], e0[4 * g4 + 1], e0[4 * g4 + 2], e0[4 * g4 + 3]};
        fvec4 o1 = {e1[4 * g4], e1[4 * g4 + 1], e1[4 * g4 + 2], e1[4 * g4 + 3]};
        *(fvec4*)(ps + swz(ql, 2 * g4 + hi)) = o0;
        *(fvec4*)(ps + swz(ql, 2 * g4 + hi + 8)) = o1;
      }
      {
        char* pg = (char*)(probs + ((size_t)(bh * CS + qbase + wv * 32)) * CG);
#pragma unroll
        for (int i = 0; i < 8; ++i) {
          const unsigned o = (unsigned)(i * 1024 + lane * 16);
          const int row = o >> 8, slot = (o >> 4) & 15;
          fvec4 x = *(const fvec4*)(ps + swz(row, slot));
          __builtin_nontemporal_store(x, (fvec4*)(pg + o));
        }
      }

      short8 pa0, pa1, pa2, pa3;
      MK_PA(pa0, hi, e0[0], e0[1], e0[2], e0[3], e0[4], e0[5], e0[6], e0[7]);
      MK_PA(pa1, hi, e0[8], e0[9], e0[10], e0[11], e0[12], e0[13], e0[14], e0[15]);
      MK_PA(pa2, hi, e1[0], e1[1], e1[2], e1[3], e1[4], e1[5], e1[6], e1[7]);
      MK_PA(pa3, hi, e1[8], e1[9], e1[10], e1[11], e1[12], e1[13], e1[14], e1[15]);

      f32x16 oc0 = zero16(), oc1 = zero16();
#pragma unroll
      for (int s = 0; s < 4; ++s) {
        const short8 pas = (s == 0) ? pa0 : (s == 1) ? pa1 : (s == 2) ? pa2 : pa3;
        oc0 = __builtin_amdgcn_mfma_f32_32x32x16_bf16(
            pas, vfrag(bV, ql, s, hi), oc0, 0, 0, 0);
        oc1 = __builtin_amdgcn_mfma_f32_32x32x16_bf16(
            pas, vfrag(bV, 32 + ql, s, hi), oc1, 0, 0, 0);
      }

      float* cb = ctx + ((size_t)(bh * CS + qbase + wv * 32)) * CD;
#pragma unroll
      for (int r = 0; r < 16; ++r) {
        const int qr2 = (r & 3) + 8 * (r >> 2) + 4 * hi;
        __builtin_nontemporal_store(oc0[r], cb + (size_t)qr2 * CD + ql);
        __builtin_nontemporal_store(oc1[r], cb + (size_t)qr2 * CD + 32 + ql);
      }
    }
  } else {
    // ============================ part 2 =================================
    const int bx2 = blockIdx.x - NS1;
    const int qt = wv & 1, kh = wv >> 1;
    const int qslot = qt * 32 + ql;

    const int gq = gpos[b * CG + qslot];
    const float* qr = q + ((size_t)(bh * CS + gq)) * CD + hi * 8;
    fvec4 qa[8];
#pragma unroll
    for (int s = 0; s < 4; ++s) {
      qa[2 * s]     = *(const fvec4*)(qr + s * 16);
      qa[2 * s + 1] = *(const fvec4*)(qr + s * 16 + 4);
    }
    short8 qf[4];
#pragma unroll
    for (int s = 0; s < 4; ++s) {
      U8 w;
      w.u[0] = pk2(qa[2 * s][0] * 0.125f, qa[2 * s][1] * 0.125f);
      w.u[1] = pk2(qa[2 * s][2] * 0.125f, qa[2 * s][3] * 0.125f);
      w.u[2] = pk2(qa[2 * s + 1][0] * 0.125f, qa[2 * s + 1][1] * 0.125f);
      w.u[3] = pk2(qa[2 * s + 1][2] * 0.125f, qa[2 * s + 1][3] * 0.125f);
      qf[s] = w.s;
    }

#pragma unroll
    for (int u = 0; u < 4; ++u) {
      const int kwin = bx2 * 512 + u * 128;
      if (u) __syncthreads();
      if (t < 128)
        stage_stream((char*)sm.p2.kf[0], (char*)sm.p2.kf[1],
                     k + (size_t)(bh * CS + kwin) * CD, t);
      else
        stage_stream((char*)sm.p2.vf[0], (char*)sm.p2.vf[1],
                     v + (size_t)(bh * CS + kwin) * CD, t - 128);
      __syncthreads();

      const char* bK = (const char*)sm.p2.kf[kh];
      const char* bV = (const char*)sm.p2.vf[kh];

      f32x16 acc0 = zero16(), acc1 = zero16();
#pragma unroll
      for (int s = 0; s < 4; ++s) {
        acc0 = __builtin_amdgcn_mfma_f32_32x32x16_bf16(
            kfrag(bK, ql, s, hi), qf[s], acc0, 0, 0, 0);
        acc1 = __builtin_amdgcn_mfma_f32_32x32x16_bf16(
            kfrag(bK, 32 + ql, s, hi), qf[s], acc1, 0, 0, 0);
      }

      float e0[16], e1[16];
      float m = -1e30f;
#pragma unroll
      for (int r = 0; r < 16; ++r) {
        e0[r] = acc0[r]; e1[r] = acc1[r];
        m = fmaxf(m, fmaxf(e0[r], e1[r]));
      }
      m = fmaxf(m, __shfl_xor(m, 32));
      float ls = 0.f;
#pragma unroll
      for (int r = 0; r < 16; ++r) {
        e0[r] = __expf(e0[r] - m); ls += e0[r];
        e1[r] = __expf(e1[r] - m); ls += e1[r];
      }
      ls += __shfl_xor(ls, 32);

      short8 pa0, pa1, pa2, pa3;
      MK_PA(pa0, hi, e0[0], e0[1], e0[2], e0[3], e0[4], e0[5], e0[6], e0[7]);
      MK_PA(pa1, hi, e0[8], e0[9], e0[10], e0[11], e0[12], e0[13], e0[14], e0[15]);
      MK_PA(pa2, hi, e1[0], e1[1], e1[2], e1[3], e1[4], e1[5], e1[6], e1[7]);
      MK_PA(pa3, hi, e1[8], e1[9], e1[10], e1[11], e1[12], e1[13], e1[14], e1[15]);

      f32x16 oc0 = zero16(), oc1 = zero16();
#pragma unroll
      for (int s = 0; s < 4; ++s) {
        const short8 pas = (s == 0) ? pa0 : (s == 1) ? pa1 : (s == 2) ? pa2 : pa3;
        oc0 = __builtin_amdgcn_mfma_f32_32x32x16_bf16(
            pas, vfrag(bV, ql, s, hi), oc0, 0, 0, 0);
        oc1 = __builtin_amdgcn_mfma_f32_32x32x16_bf16(
            pas, vfrag(bV, 32 + ql, s, hi), oc1, 0, 0, 0);
      }
      __syncthreads();

      const int part = (bx2 * 4 + u) * 2 + kh;
      if (hi == 0) {
        const size_t o = ((size_t)(bh * NPART + part)) * CG + qslot;
        __builtin_nontemporal_store(m, pm + o);
        __builtin_nontemporal_store(ls, pl + o);
      }
      unsigned short* po =
          pctx + (((size_t)(bh * NPART + part)) * CG + qt * 32) * CD;
#pragma unroll
      for (int r = 0; r < 16; ++r) {
        const int qr2 = (r & 3) + 8 * (r >> 2) + 4 * hi;
        __builtin_nontemporal_store(f2bf(oc0[r]), po + (size_t)qr2 * CD + ql);
        __builtin_nontemporal_store(f2bf(oc1[r]),
                                    po + (size_t)qr2 * CD + 32 + ql);
      }
    }
  }
}

// ---------------------------------------------------------------------------
__global__ __launch_bounds__(256) void k_combine(
    const float* __restrict__ pm, const float* __restrict__ pl,
    const unsigned short* __restrict__ pctx,
    const int* __restrict__ gpos, const int* __restrict__ gcount,
    float* __restrict__ ctx) {
  const int g = blockIdx.x;
  const int bh = blockIdx.y;
  const int b = bh / CH;
  if (g >= gcount[b]) return;
  const int t = threadIdx.x;
  const int cg = t >> 6, d = t & 63;
  __shared__ float smax[4];
  __shared__ float sl[4];
  __shared__ float sacc[4][64];

  float lm = -1e30f;
#pragma unroll
  for (int j = 0; j < 16; ++j) {
    const int c = cg * 16 + j;
    lm = fmaxf(lm, pm[((size_t)(bh * NPART + c)) * CG + g]);
  }
  if (d == 0) smax[cg] = lm;
  __syncthreads();
  const float m = fmaxf(fmaxf(smax[0], smax[1]), fmaxf(smax[2], smax[3]));

  float L = 0.f, acc = 0.f;
#pragma unroll
  for (int j = 0; j < 16; ++j) {
    const int c = cg * 16 + j;
    const size_t o = ((size_t)(bh * NPART + c)) * CG + g;
    const float w = __expf(pm[o] - m);
    L = fmaf(w, pl[o], L);
    const float x = __uint_as_float((unsigned)pctx[o * CD + d] << 16);
    acc = fmaf(w, x, acc);
  }
  sacc[cg][d] = acc;
  if (d == 0) sl[cg] = L;
  __syncthreads();
  if (cg == 0) {
    const float A = sacc[0][d] + sacc[1][d] + sacc[2][d] + sacc[3][d];
    const float Lt = sl[0] + sl[1] + sl[2] + sl[3];
    const int tok = gpos[b * CG + g];
    __builtin_nontemporal_store(A / Lt, ctx + ((size_t)(bh * CS + tok)) * CD + d);
  }
}

extern "C" void kernel_launch(void* const* d_in, const int* in_sizes, int n_in,
                              void* d_out, int out_size, void* d_ws, size_t ws_size,
                              hipStream_t stream) {
  const float* q = (const float*)d_in[0];
  const float* k = (const float*)d_in[1];
  const float* v = (const float*)d_in[2];
  const int* mask = (const int*)d_in[3];

  float* ctx = (float*)d_out;
  float* probs = ctx + (size_t)CBH * CS * CD;

  char* ws = (char*)d_ws;
  int* gpos = (int*)ws;                                  // 512 B
  int* gcount = (int*)(ws + 512);                        // 512 B
  float* pm = (float*)(ws + 1024);                       // CBH*NPART*CG f32
  float* pl = pm + (size_t)CBH * NPART * CG;             // CBH*NPART*CG f32
  unsigned short* pctx =
      (unsigned short*)(pl + (size_t)CBH * NPART * CG);  // CBH*NPART*CG*CD bf16

  k_setup<<<dim3(CB), dim3(64), 0, stream>>>(mask, gpos, gcount);
  k_main<<<dim3(NS1 + NS2, CBH), dim3(256), 0, stream>>>(
      q, k, v, gpos, gcount, ctx, probs, pm, pl, pctx);
  k_combine<<<dim3(CG, CBH), dim3(256), 0, stream>>>(
      pm, pl, pctx, gpos, gcount, ctx);
}

// Round 15
// 44.452 us; speedup vs baseline: 1.3904x; 1.3904x over previous
//
#include <hip/hip_runtime.h>
#include <cstddef>

constexpr int CB  = 2;
constexpr int CH  = 16;
constexpr int CS  = 4096;
constexpr int CD  = 64;
constexpr int CG  = 64;
constexpr int CBH = CB * CH;
constexpr int NS1 = 8;            // part-1 splits per bh (4 q-windows of 128)
constexpr int NS2 = 8;            // part-2 splits per bh (4 key-windows of 128)
constexpr int NPART = 16;         // part = bx2*2 + key-half (online over windows)

// q pre-scale: 1/sqrt(64) * log2(e)  -> softmax uses exp2 directly
#define QSCALE 0.18033688011112042f

typedef float  f32x16 __attribute__((ext_vector_type(16)));
typedef short  short8 __attribute__((ext_vector_type(8)));
typedef float  fvec4  __attribute__((ext_vector_type(4)));

union U8 { unsigned u[4]; short8 s; };

__device__ __forceinline__ unsigned short f2bf(float x) {
  unsigned u = __float_as_uint(x);
  unsigned r = u + 0x7fffu + ((u >> 16) & 1u);  // RNE
  return (unsigned short)(r >> 16);
}
__device__ __forceinline__ unsigned pk2(float lo, float hi) {
  return (unsigned)f2bf(lo) | ((unsigned)f2bf(hi) << 16);
}
__device__ __forceinline__ f32x16 zero16() {
  f32x16 z;
#pragma unroll
  for (int i = 0; i < 16; ++i) z[i] = 0.f;
  return z;
}

// P -> MFMA-A fragment relayout for one 16-key slot (exchange across lane^32).
#define MK_PA(dst, hi_, a0,a1,a2,a3,a4,a5,a6,a7)                         \
  {                                                                      \
    unsigned x0 = pk2(a0, a1), x1 = pk2(a2, a3);                         \
    unsigned y0 = pk2(a4, a5), y1 = pk2(a6, a7);                         \
    unsigned t0 = (unsigned)__shfl_xor((int)((hi_) ? x0 : y0), 32);      \
    if (hi_) x0 = t0; else y0 = t0;                                      \
    unsigned t1 = (unsigned)__shfl_xor((int)((hi_) ? x1 : y1), 32);      \
    if (hi_) x1 = t1; else y1 = t1;                                      \
    U8 w_; w_.u[0] = x0; w_.u[1] = x1; w_.u[2] = y0; w_.u[3] = y1;       \
    dst = w_.s;                                                          \
  }

// ---------------------------------------------------------------------------
__global__ __launch_bounds__(256) void k_setup(
    const int* __restrict__ mask, int* __restrict__ gpos,
    int* __restrict__ gcount) {
  const int b = blockIdx.x;
  const int t = threadIdx.x;  // 256
  __shared__ int cnt[256];
  if (t < CG) gpos[b * CG + t] = 0;
  const int span = CS / 256;
  const int base = b * CS + t * span;
  int c = 0;
  for (int i = 0; i < span; ++i) c += (mask[base + i] > 0) ? 1 : 0;
  cnt[t] = c;
  __syncthreads();
  int pre = 0;
  for (int j = 0; j < t; ++j) pre += cnt[j];
  for (int i = 0; i < span; ++i) {
    if (mask[base + i] > 0) {
      if (pre < CG) gpos[b * CG + pre] = t * span + i;
      ++pre;
    }
  }
  if (t == 255) gcount[b] = (pre < CG) ? pre : CG;
}

// ---------------------------------------------------------------------------
// Fused main kernel (512 blocks, all co-resident). bf16 LDS tiles (r12).
// blockIdx.x < NS1 : part-1 -- stage gK/gV ONCE, loop 4 q-windows of 128.
// else             : part-2 -- q once; loop 4 key-windows of 128 with
//                    register-prefetch staging; ONLINE softmax across windows
//                    (PV-space rescale via shfl); 1 flash partial per
//                    (block, key-half): NPART = 16.
// ---------------------------------------------------------------------------
struct __align__(16) SMemP1 { short sK[64 * 64]; short sVT[64 * 64]; };
struct __align__(16) SMemP2 { short sK2[2][64 * 64]; short sVT2[2][64 * 64]; };
union __align__(16) SMem { SMemP1 p1; SMemP2 p2; };

__global__ __launch_bounds__(256, 2) void k_main(
    const float* __restrict__ q, const float* __restrict__ k,
    const float* __restrict__ v,
    const int* __restrict__ gpos, const int* __restrict__ gcount,
    float* __restrict__ ctx, float* __restrict__ probs,
    float* __restrict__ pm, float* __restrict__ pl,
    unsigned short* __restrict__ pctx) {
  __shared__ SMem sm;
  const int bh = blockIdx.y, b = bh / CH, t = threadIdx.x;
  const int lane = t & 63, wv = t >> 6;
  const int hi = lane >> 5, ql = lane & 31;
  const unsigned kswz = (unsigned)((ql & 7) << 4);
  const bool isP1 = (blockIdx.x < NS1);

  if (isP1) {
    // ============================ part 1 =================================
    const int bx1 = blockIdx.x;
    const int gc = gcount[b];
    if (t < 128) {  // stage gathered K rows -> sK[key][d]
      const int row = t >> 1, c0 = (t & 1) * 32;
      const int grow = gpos[b * CG + row];
      const float* src = k + ((size_t)(bh * CS + grow)) * CD + c0;
      fvec4 ra[8];
#pragma unroll
      for (int i = 0; i < 4; ++i) {
        ra[2 * i]     = *(const fvec4*)(src + i * 8);
        ra[2 * i + 1] = *(const fvec4*)(src + i * 8 + 4);
      }
      const unsigned swz = (unsigned)((row & 7) << 4);
      char* rb = (char*)sm.p1.sK + row * 128;
#pragma unroll
      for (int i = 0; i < 4; ++i) {
        U8 w;
        w.u[0] = pk2(ra[2 * i][0], ra[2 * i][1]);
        w.u[1] = pk2(ra[2 * i][2], ra[2 * i][3]);
        w.u[2] = pk2(ra[2 * i + 1][0], ra[2 * i + 1][1]);
        w.u[3] = pk2(ra[2 * i + 1][2], ra[2 * i + 1][3]);
        *(short8*)(rb + (((unsigned)(c0 * 2 + i * 16)) ^ swz)) = w.s;
      }
    } else {  // stage gathered V transposed -> sVT[d][key]
      const int u = t - 128;
      const int kg = u >> 4, cg = u & 15;
      int gi[8];
#pragma unroll
      for (int i = 0; i < 8; ++i) gi[i] = gpos[b * CG + 8 * kg + i];
      fvec4 rv[8];
#pragma unroll
      for (int i = 0; i < 8; ++i)
        rv[i] = *(const fvec4*)(v + ((size_t)(bh * CS + gi[i])) * CD + 4 * cg);
#pragma unroll
      for (int c = 0; c < 4; ++c) {
        const int row = 4 * cg + c;
        U8 w;
        w.u[0] = pk2(rv[0][c], rv[1][c]); w.u[1] = pk2(rv[2][c], rv[3][c]);
        w.u[2] = pk2(rv[4][c], rv[5][c]); w.u[3] = pk2(rv[6][c], rv[7][c]);
        *(short8*)((char*)sm.p1.sVT + row * 128 +
                   (((unsigned)(16 * kg)) ^ ((unsigned)((row & 7) << 4)))) = w.s;
      }
    }
    __syncthreads();

#pragma unroll
    for (int it = 0; it < 4; ++it) {
      const int qbase = (bx1 * 4 + it) * 128;
      const int qrow = qbase + wv * 32 + ql;
      const float* qr = q + ((size_t)(bh * CS + qrow)) * CD + hi * 8;
      fvec4 qa[8];
#pragma unroll
      for (int s = 0; s < 4; ++s) {
        qa[2 * s]     = *(const fvec4*)(qr + s * 16);
        qa[2 * s + 1] = *(const fvec4*)(qr + s * 16 + 4);
      }
      short8 qf[4];
#pragma unroll
      for (int s = 0; s < 4; ++s) {
        U8 w;
        w.u[0] = pk2(qa[2 * s][0] * QSCALE, qa[2 * s][1] * QSCALE);
        w.u[1] = pk2(qa[2 * s][2] * QSCALE, qa[2 * s][3] * QSCALE);
        w.u[2] = pk2(qa[2 * s + 1][0] * QSCALE, qa[2 * s + 1][1] * QSCALE);
        w.u[3] = pk2(qa[2 * s + 1][2] * QSCALE, qa[2 * s + 1][3] * QSCALE);
        qf[s] = w.s;
      }

      f32x16 acc0 = zero16(), acc1 = zero16();
#pragma unroll
      for (int s = 0; s < 4; ++s) {
        const unsigned off = ((unsigned)(32 * s + 16 * hi)) ^ kswz;
        short8 k0 = *(const short8*)((char*)sm.p1.sK + ql * 128 + off);
        acc0 = __builtin_amdgcn_mfma_f32_32x32x16_bf16(k0, qf[s], acc0, 0, 0, 0);
        short8 k1 = *(const short8*)((char*)sm.p1.sK + (32 + ql) * 128 + off);
        acc1 = __builtin_amdgcn_mfma_f32_32x32x16_bf16(k1, qf[s], acc1, 0, 0, 0);
      }

      float e0[16], e1[16];
      float m = -1e30f;
#pragma unroll
      for (int r = 0; r < 16; ++r) {
        const int key0 = (r & 3) + 8 * (r >> 2) + 4 * hi;
        float x0 = (key0 < gc) ? acc0[r] : -1e30f;
        float x1 = (key0 + 32 < gc) ? acc1[r] : -1e30f;
        e0[r] = x0; e1[r] = x1;
        m = fmaxf(m, fmaxf(x0, x1));
      }
      m = fmaxf(m, __shfl_xor(m, 32));
      float ls = 0.f;
#pragma unroll
      for (int r = 0; r < 16; ++r) {
        e0[r] = __builtin_exp2f(e0[r] - m); ls += e0[r];
        e1[r] = __builtin_exp2f(e1[r] - m); ls += e1[r];
      }
      ls += __shfl_xor(ls, 32);
      const float inv = 1.0f / ls;
#pragma unroll
      for (int r = 0; r < 16; ++r) { e0[r] *= inv; e1[r] *= inv; }

      float* prow = probs + ((size_t)(bh * CS + qrow)) * CG;
#pragma unroll
      for (int g4 = 0; g4 < 4; ++g4) {
        fvec4 o0 = {e0[4 * g4], e0[4 * g4 + 1], e0[4 * g4 + 2], e0[4 * g4 + 3]};
        fvec4 o1 = {e1[4 * g4], e1[4 * g4 + 1], e1[4 * g4 + 2], e1[4 * g4 + 3]};
        *(fvec4*)(prow + 8 * g4 + 4 * hi) = o0;
        *(fvec4*)(prow + 8 * g4 + 4 * hi + 32) = o1;
      }

      short8 pa0, pa1, pa2, pa3;
      MK_PA(pa0, hi, e0[0], e0[1], e0[2], e0[3], e0[4], e0[5], e0[6], e0[7]);
      MK_PA(pa1, hi, e0[8], e0[9], e0[10], e0[11], e0[12], e0[13], e0[14], e0[15]);
      MK_PA(pa2, hi, e1[0], e1[1], e1[2], e1[3], e1[4], e1[5], e1[6], e1[7]);
      MK_PA(pa3, hi, e1[8], e1[9], e1[10], e1[11], e1[12], e1[13], e1[14], e1[15]);

      f32x16 oc0 = zero16(), oc1 = zero16();
#pragma unroll
      for (int s = 0; s < 4; ++s) {
        const short8 pas = (s == 0) ? pa0 : (s == 1) ? pa1 : (s == 2) ? pa2 : pa3;
        const unsigned off = ((unsigned)(32 * s + 16 * hi)) ^ kswz;
        short8 v0 = *(const short8*)((char*)sm.p1.sVT + ql * 128 + off);
        oc0 = __builtin_amdgcn_mfma_f32_32x32x16_bf16(pas, v0, oc0, 0, 0, 0);
        short8 v1 = *(const short8*)((char*)sm.p1.sVT + (32 + ql) * 128 + off);
        oc1 = __builtin_amdgcn_mfma_f32_32x32x16_bf16(pas, v1, oc1, 0, 0, 0);
      }

      float* cb = ctx + ((size_t)(bh * CS + qbase + wv * 32)) * CD;
#pragma unroll
      for (int r = 0; r < 16; ++r) {
        const int qr2 = (r & 3) + 8 * (r >> 2) + 4 * hi;
        cb[(size_t)qr2 * CD + ql] = oc0[r];
        cb[(size_t)qr2 * CD + 32 + ql] = oc1[r];
      }
    }
  } else {
    // ============================ part 2 =================================
    const int bx2 = blockIdx.x - NS1;
    const int qt = wv & 1, kh = wv >> 1;
    const int qslot = qt * 32 + ql;

    const int gq = gpos[b * CG + qslot];
    const float* qr = q + ((size_t)(bh * CS + gq)) * CD + hi * 8;
    fvec4 qa[8];
#pragma unroll
    for (int s = 0; s < 4; ++s) {
      qa[2 * s]     = *(const fvec4*)(qr + s * 16);
      qa[2 * s + 1] = *(const fvec4*)(qr + s * 16 + 4);
    }
    short8 qf[4];
#pragma unroll
    for (int s = 0; s < 4; ++s) {
      U8 w;
      w.u[0] = pk2(qa[2 * s][0] * QSCALE, qa[2 * s][1] * QSCALE);
      w.u[1] = pk2(qa[2 * s][2] * QSCALE, qa[2 * s][3] * QSCALE);
      w.u[2] = pk2(qa[2 * s + 1][0] * QSCALE, qa[2 * s + 1][1] * QSCALE);
      w.u[3] = pk2(qa[2 * s + 1][2] * QSCALE, qa[2 * s + 1][3] * QSCALE);
      qf[s] = w.s;
    }

    const int krow = t >> 1, kc0 = (t & 1) * 32;          // t<128 (K)
    const int vu = t - 128, vkg = vu >> 4, vcg = vu & 15; // t>=128 (V)

    fvec4 scur[16], snxt[16];
    {
      const int kwin = (bx2 * 4) * 128;
      if (t < 128) {
#pragma unroll
        for (int h = 0; h < 2; ++h) {
          const float* src =
              k + ((size_t)(bh * CS + kwin + h * 64 + krow)) * CD + kc0;
#pragma unroll
          for (int i = 0; i < 4; ++i) {
            scur[h * 8 + 2 * i]     = *(const fvec4*)(src + i * 8);
            scur[h * 8 + 2 * i + 1] = *(const fvec4*)(src + i * 8 + 4);
          }
        }
      } else {
#pragma unroll
        for (int h = 0; h < 2; ++h)
#pragma unroll
          for (int i = 0; i < 8; ++i)
            scur[h * 8 + i] = *(const fvec4*)(
                v + ((size_t)(bh * CS + kwin + h * 64 + 8 * vkg + i)) * CD +
                4 * vcg);
      }
    }

    // online-softmax state (QK-space: lane = q) + PV accumulators
    float m = -1e30f, l = 0.f;
    f32x16 oc0 = zero16(), oc1 = zero16();

#pragma unroll
    for (int u = 0; u < 4; ++u) {
      // convert + ds_write current window
      if (t < 128) {
        const unsigned swz = (unsigned)((krow & 7) << 4);
#pragma unroll
        for (int h = 0; h < 2; ++h) {
          char* rb = (char*)sm.p2.sK2[h] + krow * 128;
#pragma unroll
          for (int i = 0; i < 4; ++i) {
            U8 w;
            w.u[0] = pk2(scur[h * 8 + 2 * i][0], scur[h * 8 + 2 * i][1]);
            w.u[1] = pk2(scur[h * 8 + 2 * i][2], scur[h * 8 + 2 * i][3]);
            w.u[2] = pk2(scur[h * 8 + 2 * i + 1][0], scur[h * 8 + 2 * i + 1][1]);
            w.u[3] = pk2(scur[h * 8 + 2 * i + 1][2], scur[h * 8 + 2 * i + 1][3]);
            *(short8*)(rb + (((unsigned)(kc0 * 2 + i * 16)) ^ swz)) = w.s;
          }
        }
      } else {
#pragma unroll
        for (int h = 0; h < 2; ++h)
#pragma unroll
          for (int c = 0; c < 4; ++c) {
            const int row = 4 * vcg + c;
            U8 w;
            w.u[0] = pk2(scur[h * 8 + 0][c], scur[h * 8 + 1][c]);
            w.u[1] = pk2(scur[h * 8 + 2][c], scur[h * 8 + 3][c]);
            w.u[2] = pk2(scur[h * 8 + 4][c], scur[h * 8 + 5][c]);
            w.u[3] = pk2(scur[h * 8 + 6][c], scur[h * 8 + 7][c]);
            *(short8*)((char*)sm.p2.sVT2[h] + row * 128 +
                       (((unsigned)(16 * vkg)) ^
                        ((unsigned)((row & 7) << 4)))) = w.s;
          }
      }
      __syncthreads();

      // issue next window's loads (overlap with compute)
      if (u < 3) {
        const int kwin = (bx2 * 4 + u + 1) * 128;
        if (t < 128) {
#pragma unroll
          for (int h = 0; h < 2; ++h) {
            const float* src =
                k + ((size_t)(bh * CS + kwin + h * 64 + krow)) * CD + kc0;
#pragma unroll
            for (int i = 0; i < 4; ++i) {
              snxt[h * 8 + 2 * i]     = *(const fvec4*)(src + i * 8);
              snxt[h * 8 + 2 * i + 1] = *(const fvec4*)(src + i * 8 + 4);
            }
          }
        } else {
#pragma unroll
          for (int h = 0; h < 2; ++h)
#pragma unroll
            for (int i = 0; i < 8; ++i)
              snxt[h * 8 + i] = *(const fvec4*)(
                  v + ((size_t)(bh * CS + kwin + h * 64 + 8 * vkg + i)) * CD +
                  4 * vcg);
        }
      }

      // compute window u (wave's 64-key half) with online update
      const char* bK = (const char*)sm.p2.sK2[kh];
      const char* bVT = (const char*)sm.p2.sVT2[kh];

      f32x16 acc0 = zero16(), acc1 = zero16();
#pragma unroll
      for (int s = 0; s < 4; ++s) {
        const unsigned off = ((unsigned)(32 * s + 16 * hi)) ^ kswz;
        short8 k0 = *(const short8*)(bK + ql * 128 + off);
        acc0 = __builtin_amdgcn_mfma_f32_32x32x16_bf16(k0, qf[s], acc0, 0, 0, 0);
        short8 k1 = *(const short8*)(bK + (32 + ql) * 128 + off);
        acc1 = __builtin_amdgcn_mfma_f32_32x32x16_bf16(k1, qf[s], acc1, 0, 0, 0);
      }

      float e0[16], e1[16];
      float tm = -1e30f;
#pragma unroll
      for (int r = 0; r < 16; ++r) {
        e0[r] = acc0[r]; e1[r] = acc1[r];
        tm = fmaxf(tm, fmaxf(e0[r], e1[r]));
      }
      tm = fmaxf(tm, __shfl_xor(tm, 32));
      const float mnew = fmaxf(m, tm);
      const float rs = __builtin_exp2f(m - mnew);   // QK-space (per q = ql)
      l *= rs;
      float add = 0.f;
#pragma unroll
      for (int r = 0; r < 16; ++r) {
        e0[r] = __builtin_exp2f(e0[r] - mnew); add += e0[r];
        e1[r] = __builtin_exp2f(e1[r] - mnew); add += e1[r];
      }
      add += __shfl_xor(add, 32);
      l += add;
      m = mnew;

      // PV-space rescale: oc regs hold q = crow(r,hi); fetch that q's rs.
      // rs is hi-uniform (post shfl_xor reduce), sources are lanes < 32.
      float rsf[16];
#pragma unroll
      for (int r = 0; r < 16; ++r) {
        const int qr2 = (r & 3) + 8 * (r >> 2) + 4 * hi;
        rsf[r] = __shfl(rs, qr2);
      }
#pragma unroll
      for (int r = 0; r < 16; ++r) { oc0[r] *= rsf[r]; oc1[r] *= rsf[r]; }

      short8 pa0, pa1, pa2, pa3;
      MK_PA(pa0, hi, e0[0], e0[1], e0[2], e0[3], e0[4], e0[5], e0[6], e0[7]);
      MK_PA(pa1, hi, e0[8], e0[9], e0[10], e0[11], e0[12], e0[13], e0[14], e0[15]);
      MK_PA(pa2, hi, e1[0], e1[1], e1[2], e1[3], e1[4], e1[5], e1[6], e1[7]);
      MK_PA(pa3, hi, e1[8], e1[9], e1[10], e1[11], e1[12], e1[13], e1[14], e1[15]);

#pragma unroll
      for (int s = 0; s < 4; ++s) {
        const short8 pas = (s == 0) ? pa0 : (s == 1) ? pa1 : (s == 2) ? pa2 : pa3;
        const unsigned off = ((unsigned)(32 * s + 16 * hi)) ^ kswz;
        short8 v0 = *(const short8*)(bVT + ql * 128 + off);
        oc0 = __builtin_amdgcn_mfma_f32_32x32x16_bf16(pas, v0, oc0, 0, 0, 0);
        short8 v1 = *(const short8*)(bVT + (32 + ql) * 128 + off);
        oc1 = __builtin_amdgcn_mfma_f32_32x32x16_bf16(pas, v1, oc1, 0, 0, 0);
      }
      __syncthreads();  // LDS consumed before next iteration's ds_write

      if (u < 3) {
#pragma unroll
        for (int i = 0; i < 16; ++i) scur[i] = snxt[i];
      }
    }

    // epilogue: ONE flash partial per (block, key-half). NPART = 16.
    const int part = bx2 * 2 + kh;
    if (hi == 0) {
      const size_t o = ((size_t)(bh * NPART + part)) * CG + qslot;
      pm[o] = m;   // log2-units
      pl[o] = l;
    }
    unsigned short* po =
        pctx + (((size_t)(bh * NPART + part)) * CG + qt * 32) * CD;
#pragma unroll
    for (int r = 0; r < 16; ++r) {
      const int qr2 = (r & 3) + 8 * (r >> 2) + 4 * hi;
      po[(size_t)qr2 * CD + ql] = f2bf(oc0[r]);
      po[(size_t)qr2 * CD + 32 + ql] = f2bf(oc1[r]);
    }
  }
}

// ---------------------------------------------------------------------------
// Combine: 256 threads = 4 c-groups x 64 d; NPART=16 -> 4 chains per group.
// pm is in log2-units -> exp2 weights.
// ---------------------------------------------------------------------------
__global__ __launch_bounds__(256) void k_combine(
    const float* __restrict__ pm, const float* __restrict__ pl,
    const unsigned short* __restrict__ pctx,
    const int* __restrict__ gpos, const int* __restrict__ gcount,
    float* __restrict__ ctx) {
  const int g = blockIdx.x;
  const int bh = blockIdx.y;
  const int b = bh / CH;
  if (g >= gcount[b]) return;
  const int t = threadIdx.x;
  const int cg = t >> 6, d = t & 63;
  __shared__ float smax[4];
  __shared__ float sl[4];
  __shared__ float sacc[4][64];

  float lm = -1e30f;
#pragma unroll
  for (int j = 0; j < 4; ++j) {
    const int c = cg * 4 + j;
    lm = fmaxf(lm, pm[((size_t)(bh * NPART + c)) * CG + g]);
  }
  if (d == 0) smax[cg] = lm;
  __syncthreads();
  const float m = fmaxf(fmaxf(smax[0], smax[1]), fmaxf(smax[2], smax[3]));

  float L = 0.f, acc = 0.f;
#pragma unroll
  for (int j = 0; j < 4; ++j) {
    const int c = cg * 4 + j;
    const size_t o = ((size_t)(bh * NPART + c)) * CG + g;
    const float w = __builtin_exp2f(pm[o] - m);
    L = fmaf(w, pl[o], L);
    const float x = __uint_as_float((unsigned)pctx[o * CD + d] << 16);
    acc = fmaf(w, x, acc);
  }
  sacc[cg][d] = acc;
  if (d == 0) sl[cg] = L;
  __syncthreads();
  if (cg == 0) {
    const float A = sacc[0][d] + sacc[1][d] + sacc[2][d] + sacc[3][d];
    const float Lt = sl[0] + sl[1] + sl[2] + sl[3];
    const int tok = gpos[b * CG + g];
    ctx[((size_t)(bh * CS + tok)) * CD + d] = A / Lt;
  }
}

extern "C" void kernel_launch(void* const* d_in, const int* in_sizes, int n_in,
                              void* d_out, int out_size, void* d_ws, size_t ws_size,
                              hipStream_t stream) {
  const float* q = (const float*)d_in[0];
  const float* k = (const float*)d_in[1];
  const float* v = (const float*)d_in[2];
  const int* mask = (const int*)d_in[3];

  float* ctx = (float*)d_out;
  float* probs = ctx + (size_t)CBH * CS * CD;

  char* ws = (char*)d_ws;
  int* gpos = (int*)ws;                                  // 512 B
  int* gcount = (int*)(ws + 512);                        // 512 B
  float* pm = (float*)(ws + 1024);                       // CBH*NPART*CG f32
  float* pl = pm + (size_t)CBH * NPART * CG;             // CBH*NPART*CG f32
  unsigned short* pctx =
      (unsigned short*)(pl + (size_t)CBH * NPART * CG);  // CBH*NPART*CG*CD bf16

  k_setup<<<dim3(CB), dim3(256), 0, stream>>>(mask, gpos, gcount);
  k_main<<<dim3(NS1 + NS2, CBH), dim3(256), 0, stream>>>(
      q, k, v, gpos, gcount, ctx, probs, pm, pl, pctx);
  k_combine<<<dim3(CG, CBH), dim3(256), 0, stream>>>(
      pm, pl, pctx, gpos, gcount, ctx);
}

// Round 16
// 40.665 us; speedup vs baseline: 1.5199x; 1.0931x over previous
//
#include <hip/hip_runtime.h>
#include <hip/hip_bf16.h>
#include <cstddef>

constexpr int CB  = 2;
constexpr int CH  = 16;
constexpr int CS  = 4096;
constexpr int CD  = 64;
constexpr int CG  = 64;
constexpr int CBH = CB * CH;
constexpr int NS1 = 8;            // part-1 splits per bh (4 q-windows of 128)
constexpr int NS2 = 8;            // part-2 splits per bh (4 key-windows of 128)
constexpr int NPART = 16;         // part = bx2*2 + key-half (online over windows)

// q pre-scale: 1/sqrt(64) * log2(e)  -> softmax uses exp2 directly
#define QSCALE 0.18033688011112042f

typedef float  f32x16 __attribute__((ext_vector_type(16)));
typedef short  short8 __attribute__((ext_vector_type(8)));
typedef float  fvec4  __attribute__((ext_vector_type(4)));

union U8 { unsigned u[4]; short8 s; };

// HW bf16 conversion (compiler emits v_cvt_pk_bf16_f32; RNE)
__device__ __forceinline__ unsigned short f2bf(float x) {
  union { __hip_bfloat16 h; unsigned short u; } cv;
  cv.h = __float2bfloat16(x);
  return cv.u;
}
__device__ __forceinline__ unsigned pk2(float lo, float hi) {
  union { __hip_bfloat162 h; unsigned u; } cv;
  cv.h.x = __float2bfloat16(lo);
  cv.h.y = __float2bfloat16(hi);
  return cv.u;
}
__device__ __forceinline__ f32x16 zero16() {
  f32x16 z;
#pragma unroll
  for (int i = 0; i < 16; ++i) z[i] = 0.f;
  return z;
}

// P -> MFMA-A fragment relayout for one 16-key slot (exchange across lane^32).
#define MK_PA(dst, hi_, a0,a1,a2,a3,a4,a5,a6,a7)                         \
  {                                                                      \
    unsigned x0 = pk2(a0, a1), x1 = pk2(a2, a3);                         \
    unsigned y0 = pk2(a4, a5), y1 = pk2(a6, a7);                         \
    unsigned t0 = (unsigned)__shfl_xor((int)((hi_) ? x0 : y0), 32);      \
    if (hi_) x0 = t0; else y0 = t0;                                      \
    unsigned t1 = (unsigned)__shfl_xor((int)((hi_) ? x1 : y1), 32);      \
    if (hi_) x1 = t1; else y1 = t1;                                      \
    U8 w_; w_.u[0] = x0; w_.u[1] = x1; w_.u[2] = y0; w_.u[3] = y1;       \
    dst = w_.s;                                                          \
  }

// ---------------------------------------------------------------------------
// Fused main kernel (512 blocks). Each block computes the gpos prefix-scan
// itself (shfl-scan, mask L2-hot) -- no setup kernel. Part-2 bx2==0 blocks
// export gpos/gcount to ws for k_combine.
// blockIdx.x < NS1 : part-1 -- stage gK/gV ONCE, loop 4 q-windows of 128.
// else             : part-2 -- q once; loop 4 key-windows of 128 with
//                    register-prefetch staging; ONLINE softmax across windows
//                    (PV-space rescale via shfl); NPART = 16.
// ---------------------------------------------------------------------------
struct __align__(16) SMemP1 { short sK[64 * 64]; short sVT[64 * 64]; };
struct __align__(16) SMemP2 { short sK2[2][64 * 64]; short sVT2[2][64 * 64]; };
union __align__(16) SMem { SMemP1 p1; SMemP2 p2; };

__global__ __launch_bounds__(256, 2) void k_main(
    const float* __restrict__ q, const float* __restrict__ k,
    const float* __restrict__ v, const int* __restrict__ mask,
    float* __restrict__ ctx, float* __restrict__ probs,
    float* __restrict__ pm, float* __restrict__ pl,
    unsigned short* __restrict__ pctx,
    int* __restrict__ gpos_ws, int* __restrict__ gcount_ws) {
  __shared__ SMem sm;
  __shared__ int gp[CG];
  __shared__ int gc_s;
  __shared__ int wsum[4];
  const int bh = blockIdx.y, b = bh / CH, t = threadIdx.x;
  const int lane = t & 63, wv = t >> 6;
  const int hi = lane >> 5, ql = lane & 31;
  const unsigned kswz = (unsigned)((ql & 7) << 4);
  const bool isP1 = (blockIdx.x < NS1);

  // ---- per-block gpos scan (replaces k_setup) ----
  {
    if (t < CG) gp[t] = 0;
    const int4* mp = (const int4*)(mask + b * CS + t * 16);
    int4 mv[4];
#pragma unroll
    for (int i = 0; i < 4; ++i) mv[i] = mp[i];
    int bits = 0, c = 0;
#pragma unroll
    for (int i = 0; i < 4; ++i) {
      const int4 m4 = mv[i];
      const int b0 = (m4.x > 0), b1 = (m4.y > 0), b2 = (m4.z > 0), b3 = (m4.w > 0);
      bits |= (b0 | (b1 << 1) | (b2 << 2) | (b3 << 3)) << (4 * i);
      c += b0 + b1 + b2 + b3;
    }
    int x = c;
#pragma unroll
    for (int d = 1; d < 64; d <<= 1) {
      const int y = __shfl_up(x, d);
      if (lane >= d) x += y;
    }
    if (lane == 63) wsum[wv] = x;
    __syncthreads();
    int pre = x - c;
    for (int w = 0; w < wv; ++w) pre += wsum[w];
#pragma unroll
    for (int i = 0; i < 16; ++i) {
      if (bits & (1 << i)) {
        if (pre < CG) gp[pre] = t * 16 + i;
        ++pre;
      }
    }
    if (t == 255) gc_s = (pre < CG) ? pre : CG;
    __syncthreads();
  }

  if (isP1) {
    // ============================ part 1 =================================
    const int bx1 = blockIdx.x;
    const int gc = gc_s;
    if (t < 128) {  // stage gathered K rows -> sK[key][d]
      const int row = t >> 1, c0 = (t & 1) * 32;
      const int grow = gp[row];
      const float* src = k + ((size_t)(bh * CS + grow)) * CD + c0;
      fvec4 ra[8];
#pragma unroll
      for (int i = 0; i < 4; ++i) {
        ra[2 * i]     = *(const fvec4*)(src + i * 8);
        ra[2 * i + 1] = *(const fvec4*)(src + i * 8 + 4);
      }
      const unsigned swz = (unsigned)((row & 7) << 4);
      char* rb = (char*)sm.p1.sK + row * 128;
#pragma unroll
      for (int i = 0; i < 4; ++i) {
        U8 w;
        w.u[0] = pk2(ra[2 * i][0], ra[2 * i][1]);
        w.u[1] = pk2(ra[2 * i][2], ra[2 * i][3]);
        w.u[2] = pk2(ra[2 * i + 1][0], ra[2 * i + 1][1]);
        w.u[3] = pk2(ra[2 * i + 1][2], ra[2 * i + 1][3]);
        *(short8*)(rb + (((unsigned)(c0 * 2 + i * 16)) ^ swz)) = w.s;
      }
    } else {  // stage gathered V transposed -> sVT[d][key]
      const int u = t - 128;
      const int kg = u >> 4, cg = u & 15;
      int gi[8];
#pragma unroll
      for (int i = 0; i < 8; ++i) gi[i] = gp[8 * kg + i];
      fvec4 rv[8];
#pragma unroll
      for (int i = 0; i < 8; ++i)
        rv[i] = *(const fvec4*)(v + ((size_t)(bh * CS + gi[i])) * CD + 4 * cg);
#pragma unroll
      for (int c = 0; c < 4; ++c) {
        const int row = 4 * cg + c;
        U8 w;
        w.u[0] = pk2(rv[0][c], rv[1][c]); w.u[1] = pk2(rv[2][c], rv[3][c]);
        w.u[2] = pk2(rv[4][c], rv[5][c]); w.u[3] = pk2(rv[6][c], rv[7][c]);
        *(short8*)((char*)sm.p1.sVT + row * 128 +
                   (((unsigned)(16 * kg)) ^ ((unsigned)((row & 7) << 4)))) = w.s;
      }
    }
    __syncthreads();

#pragma unroll
    for (int it = 0; it < 4; ++it) {
      const int qbase = (bx1 * 4 + it) * 128;
      const int qrow = qbase + wv * 32 + ql;
      const float* qr = q + ((size_t)(bh * CS + qrow)) * CD + hi * 8;
      fvec4 qa[8];
#pragma unroll
      for (int s = 0; s < 4; ++s) {
        qa[2 * s]     = *(const fvec4*)(qr + s * 16);
        qa[2 * s + 1] = *(const fvec4*)(qr + s * 16 + 4);
      }
      short8 qf[4];
#pragma unroll
      for (int s = 0; s < 4; ++s) {
        U8 w;
        w.u[0] = pk2(qa[2 * s][0] * QSCALE, qa[2 * s][1] * QSCALE);
        w.u[1] = pk2(qa[2 * s][2] * QSCALE, qa[2 * s][3] * QSCALE);
        w.u[2] = pk2(qa[2 * s + 1][0] * QSCALE, qa[2 * s + 1][1] * QSCALE);
        w.u[3] = pk2(qa[2 * s + 1][2] * QSCALE, qa[2 * s + 1][3] * QSCALE);
        qf[s] = w.s;
      }

      f32x16 acc0 = zero16(), acc1 = zero16();
#pragma unroll
      for (int s = 0; s < 4; ++s) {
        const unsigned off = ((unsigned)(32 * s + 16 * hi)) ^ kswz;
        short8 k0 = *(const short8*)((char*)sm.p1.sK + ql * 128 + off);
        acc0 = __builtin_amdgcn_mfma_f32_32x32x16_bf16(k0, qf[s], acc0, 0, 0, 0);
        short8 k1 = *(const short8*)((char*)sm.p1.sK + (32 + ql) * 128 + off);
        acc1 = __builtin_amdgcn_mfma_f32_32x32x16_bf16(k1, qf[s], acc1, 0, 0, 0);
      }

      float e0[16], e1[16];
      float m = -1e30f;
#pragma unroll
      for (int r = 0; r < 16; ++r) {
        const int key0 = (r & 3) + 8 * (r >> 2) + 4 * hi;
        float x0 = (key0 < gc) ? acc0[r] : -1e30f;
        float x1 = (key0 + 32 < gc) ? acc1[r] : -1e30f;
        e0[r] = x0; e1[r] = x1;
        m = fmaxf(m, fmaxf(x0, x1));
      }
      m = fmaxf(m, __shfl_xor(m, 32));
      float ls = 0.f;
#pragma unroll
      for (int r = 0; r < 16; ++r) {
        e0[r] = __builtin_exp2f(e0[r] - m); ls += e0[r];
        e1[r] = __builtin_exp2f(e1[r] - m); ls += e1[r];
      }
      ls += __shfl_xor(ls, 32);
      const float inv = 1.0f / ls;
#pragma unroll
      for (int r = 0; r < 16; ++r) { e0[r] *= inv; e1[r] *= inv; }

      float* prow = probs + ((size_t)(bh * CS + qrow)) * CG;
#pragma unroll
      for (int g4 = 0; g4 < 4; ++g4) {
        fvec4 o0 = {e0[4 * g4], e0[4 * g4 + 1], e0[4 * g4 + 2], e0[4 * g4 + 3]};
        fvec4 o1 = {e1[4 * g4], e1[4 * g4 + 1], e1[4 * g4 + 2], e1[4 * g4 + 3]};
        *(fvec4*)(prow + 8 * g4 + 4 * hi) = o0;
        *(fvec4*)(prow + 8 * g4 + 4 * hi + 32) = o1;
      }

      short8 pa0, pa1, pa2, pa3;
      MK_PA(pa0, hi, e0[0], e0[1], e0[2], e0[3], e0[4], e0[5], e0[6], e0[7]);
      MK_PA(pa1, hi, e0[8], e0[9], e0[10], e0[11], e0[12], e0[13], e0[14], e0[15]);
      MK_PA(pa2, hi, e1[0], e1[1], e1[2], e1[3], e1[4], e1[5], e1[6], e1[7]);
      MK_PA(pa3, hi, e1[8], e1[9], e1[10], e1[11], e1[12], e1[13], e1[14], e1[15]);

      f32x16 oc0 = zero16(), oc1 = zero16();
#pragma unroll
      for (int s = 0; s < 4; ++s) {
        const short8 pas = (s == 0) ? pa0 : (s == 1) ? pa1 : (s == 2) ? pa2 : pa3;
        const unsigned off = ((unsigned)(32 * s + 16 * hi)) ^ kswz;
        short8 v0 = *(const short8*)((char*)sm.p1.sVT + ql * 128 + off);
        oc0 = __builtin_amdgcn_mfma_f32_32x32x16_bf16(pas, v0, oc0, 0, 0, 0);
        short8 v1 = *(const short8*)((char*)sm.p1.sVT + (32 + ql) * 128 + off);
        oc1 = __builtin_amdgcn_mfma_f32_32x32x16_bf16(pas, v1, oc1, 0, 0, 0);
      }

      float* cb = ctx + ((size_t)(bh * CS + qbase + wv * 32)) * CD;
#pragma unroll
      for (int r = 0; r < 16; ++r) {
        const int qr2 = (r & 3) + 8 * (r >> 2) + 4 * hi;
        cb[(size_t)qr2 * CD + ql] = oc0[r];
        cb[(size_t)qr2 * CD + 32 + ql] = oc1[r];
      }
    }
  } else {
    // ============================ part 2 =================================
    const int bx2 = blockIdx.x - NS1;
    const int qt = wv & 1, kh = wv >> 1;
    const int qslot = qt * 32 + ql;

    // export gpos/gcount for k_combine (one block per bh)
    if (bx2 == 0) {
      if (t < CG) gpos_ws[b * CG + t] = gp[t];
      if (t == 0) gcount_ws[b] = gc_s;
    }

    const int gq = gp[qslot];
    const float* qr = q + ((size_t)(bh * CS + gq)) * CD + hi * 8;
    fvec4 qa[8];
#pragma unroll
    for (int s = 0; s < 4; ++s) {
      qa[2 * s]     = *(const fvec4*)(qr + s * 16);
      qa[2 * s + 1] = *(const fvec4*)(qr + s * 16 + 4);
    }
    short8 qf[4];
#pragma unroll
    for (int s = 0; s < 4; ++s) {
      U8 w;
      w.u[0] = pk2(qa[2 * s][0] * QSCALE, qa[2 * s][1] * QSCALE);
      w.u[1] = pk2(qa[2 * s][2] * QSCALE, qa[2 * s][3] * QSCALE);
      w.u[2] = pk2(qa[2 * s + 1][0] * QSCALE, qa[2 * s + 1][1] * QSCALE);
      w.u[3] = pk2(qa[2 * s + 1][2] * QSCALE, qa[2 * s + 1][3] * QSCALE);
      qf[s] = w.s;
    }

    const int krow = t >> 1, kc0 = (t & 1) * 32;          // t<128 (K)
    const int vu = t - 128, vkg = vu >> 4, vcg = vu & 15; // t>=128 (V)

    fvec4 scur[16], snxt[16];
    {
      const int kwin = (bx2 * 4) * 128;
      if (t < 128) {
#pragma unroll
        for (int h = 0; h < 2; ++h) {
          const float* src =
              k + ((size_t)(bh * CS + kwin + h * 64 + krow)) * CD + kc0;
#pragma unroll
          for (int i = 0; i < 4; ++i) {
            scur[h * 8 + 2 * i]     = *(const fvec4*)(src + i * 8);
            scur[h * 8 + 2 * i + 1] = *(const fvec4*)(src + i * 8 + 4);
          }
        }
      } else {
#pragma unroll
        for (int h = 0; h < 2; ++h)
#pragma unroll
          for (int i = 0; i < 8; ++i)
            scur[h * 8 + i] = *(const fvec4*)(
                v + ((size_t)(bh * CS + kwin + h * 64 + 8 * vkg + i)) * CD +
                4 * vcg);
      }
    }

    float m = -1e30f, l = 0.f;
    f32x16 oc0 = zero16(), oc1 = zero16();

#pragma unroll
    for (int u = 0; u < 4; ++u) {
      // convert + ds_write current window
      if (t < 128) {
        const unsigned swz = (unsigned)((krow & 7) << 4);
#pragma unroll
        for (int h = 0; h < 2; ++h) {
          char* rb = (char*)sm.p2.sK2[h] + krow * 128;
#pragma unroll
          for (int i = 0; i < 4; ++i) {
            U8 w;
            w.u[0] = pk2(scur[h * 8 + 2 * i][0], scur[h * 8 + 2 * i][1]);
            w.u[1] = pk2(scur[h * 8 + 2 * i][2], scur[h * 8 + 2 * i][3]);
            w.u[2] = pk2(scur[h * 8 + 2 * i + 1][0], scur[h * 8 + 2 * i + 1][1]);
            w.u[3] = pk2(scur[h * 8 + 2 * i + 1][2], scur[h * 8 + 2 * i + 1][3]);
            *(short8*)(rb + (((unsigned)(kc0 * 2 + i * 16)) ^ swz)) = w.s;
          }
        }
      } else {
#pragma unroll
        for (int h = 0; h < 2; ++h)
#pragma unroll
          for (int c = 0; c < 4; ++c) {
            const int row = 4 * vcg + c;
            U8 w;
            w.u[0] = pk2(scur[h * 8 + 0][c], scur[h * 8 + 1][c]);
            w.u[1] = pk2(scur[h * 8 + 2][c], scur[h * 8 + 3][c]);
            w.u[2] = pk2(scur[h * 8 + 4][c], scur[h * 8 + 5][c]);
            w.u[3] = pk2(scur[h * 8 + 6][c], scur[h * 8 + 7][c]);
            *(short8*)((char*)sm.p2.sVT2[h] + row * 128 +
                       (((unsigned)(16 * vkg)) ^
                        ((unsigned)((row & 7) << 4)))) = w.s;
          }
      }
      __syncthreads();

      // issue next window's loads (overlap with compute)
      if (u < 3) {
        const int kwin = (bx2 * 4 + u + 1) * 128;
        if (t < 128) {
#pragma unroll
          for (int h = 0; h < 2; ++h) {
            const float* src =
                k + ((size_t)(bh * CS + kwin + h * 64 + krow)) * CD + kc0;
#pragma unroll
            for (int i = 0; i < 4; ++i) {
              snxt[h * 8 + 2 * i]     = *(const fvec4*)(src + i * 8);
              snxt[h * 8 + 2 * i + 1] = *(const fvec4*)(src + i * 8 + 4);
            }
          }
        } else {
#pragma unroll
          for (int h = 0; h < 2; ++h)
#pragma unroll
            for (int i = 0; i < 8; ++i)
              snxt[h * 8 + i] = *(const fvec4*)(
                  v + ((size_t)(bh * CS + kwin + h * 64 + 8 * vkg + i)) * CD +
                  4 * vcg);
        }
      }

      // compute window u (wave's 64-key half) with online update
      const char* bK = (const char*)sm.p2.sK2[kh];
      const char* bVT = (const char*)sm.p2.sVT2[kh];

      f32x16 acc0 = zero16(), acc1 = zero16();
#pragma unroll
      for (int s = 0; s < 4; ++s) {
        const unsigned off = ((unsigned)(32 * s + 16 * hi)) ^ kswz;
        short8 k0 = *(const short8*)(bK + ql * 128 + off);
        acc0 = __builtin_amdgcn_mfma_f32_32x32x16_bf16(k0, qf[s], acc0, 0, 0, 0);
        short8 k1 = *(const short8*)(bK + (32 + ql) * 128 + off);
        acc1 = __builtin_amdgcn_mfma_f32_32x32x16_bf16(k1, qf[s], acc1, 0, 0, 0);
      }

      float e0[16], e1[16];
      float tm = -1e30f;
#pragma unroll
      for (int r = 0; r < 16; ++r) {
        e0[r] = acc0[r]; e1[r] = acc1[r];
        tm = fmaxf(tm, fmaxf(e0[r], e1[r]));
      }
      tm = fmaxf(tm, __shfl_xor(tm, 32));
      const float mnew = fmaxf(m, tm);
      const float rs = __builtin_exp2f(m - mnew);   // QK-space (per q = ql)
      l *= rs;
      float add = 0.f;
#pragma unroll
      for (int r = 0; r < 16; ++r) {
        e0[r] = __builtin_exp2f(e0[r] - mnew); add += e0[r];
        e1[r] = __builtin_exp2f(e1[r] - mnew); add += e1[r];
      }
      add += __shfl_xor(add, 32);
      l += add;
      m = mnew;

      // PV-space rescale: oc regs hold q = crow(r,hi); fetch that q's rs.
      float rsf[16];
#pragma unroll
      for (int r = 0; r < 16; ++r) {
        const int qr2 = (r & 3) + 8 * (r >> 2) + 4 * hi;
        rsf[r] = __shfl(rs, qr2);
      }
#pragma unroll
      for (int r = 0; r < 16; ++r) { oc0[r] *= rsf[r]; oc1[r] *= rsf[r]; }

      short8 pa0, pa1, pa2, pa3;
      MK_PA(pa0, hi, e0[0], e0[1], e0[2], e0[3], e0[4], e0[5], e0[6], e0[7]);
      MK_PA(pa1, hi, e0[8], e0[9], e0[10], e0[11], e0[12], e0[13], e0[14], e0[15]);
      MK_PA(pa2, hi, e1[0], e1[1], e1[2], e1[3], e1[4], e1[5], e1[6], e1[7]);
      MK_PA(pa3, hi, e1[8], e1[9], e1[10], e1[11], e1[12], e1[13], e1[14], e1[15]);

#pragma unroll
      for (int s = 0; s < 4; ++s) {
        const short8 pas = (s == 0) ? pa0 : (s == 1) ? pa1 : (s == 2) ? pa2 : pa3;
        const unsigned off = ((unsigned)(32 * s + 16 * hi)) ^ kswz;
        short8 v0 = *(const short8*)(bVT + ql * 128 + off);
        oc0 = __builtin_amdgcn_mfma_f32_32x32x16_bf16(pas, v0, oc0, 0, 0, 0);
        short8 v1 = *(const short8*)(bVT + (32 + ql) * 128 + off);
        oc1 = __builtin_amdgcn_mfma_f32_32x32x16_bf16(pas, v1, oc1, 0, 0, 0);
      }
      __syncthreads();  // LDS consumed before next iteration's ds_write

      if (u < 3) {
#pragma unroll
        for (int i = 0; i < 16; ++i) scur[i] = snxt[i];
      }
    }

    // epilogue: ONE flash partial per (block, key-half). NPART = 16.
    const int part = bx2 * 2 + kh;
    if (hi == 0) {
      const size_t o = ((size_t)(bh * NPART + part)) * CG + qslot;
      pm[o] = m;   // log2-units
      pl[o] = l;
    }
    unsigned short* po =
        pctx + (((size_t)(bh * NPART + part)) * CG + qt * 32) * CD;
#pragma unroll
    for (int r = 0; r < 16; ++r) {
      const int qr2 = (r & 3) + 8 * (r >> 2) + 4 * hi;
      po[(size_t)qr2 * CD + ql] = f2bf(oc0[r]);
      po[(size_t)qr2 * CD + 32 + ql] = f2bf(oc1[r]);
    }
  }
}

// ---------------------------------------------------------------------------
// Combine: 256 threads = 4 c-groups x 64 d; NPART=16 -> 4 chains per group.
// pm is in log2-units -> exp2 weights.
// ---------------------------------------------------------------------------
__global__ __launch_bounds__(256) void k_combine(
    const float* __restrict__ pm, const float* __restrict__ pl,
    const unsigned short* __restrict__ pctx,
    const int* __restrict__ gpos, const int* __restrict__ gcount,
    float* __restrict__ ctx) {
  const int g = blockIdx.x;
  const int bh = blockIdx.y;
  const int b = bh / CH;
  if (g >= gcount[b]) return;
  const int t = threadIdx.x;
  const int cg = t >> 6, d = t & 63;
  __shared__ float smax[4];
  __shared__ float sl[4];
  __shared__ float sacc[4][64];

  float lm = -1e30f;
#pragma unroll
  for (int j = 0; j < 4; ++j) {
    const int c = cg * 4 + j;
    lm = fmaxf(lm, pm[((size_t)(bh * NPART + c)) * CG + g]);
  }
  if (d == 0) smax[cg] = lm;
  __syncthreads();
  const float m = fmaxf(fmaxf(smax[0], smax[1]), fmaxf(smax[2], smax[3]));

  float L = 0.f, acc = 0.f;
#pragma unroll
  for (int j = 0; j < 4; ++j) {
    const int c = cg * 4 + j;
    const size_t o = ((size_t)(bh * NPART + c)) * CG + g;
    const float w = __builtin_exp2f(pm[o] - m);
    L = fmaf(w, pl[o], L);
    const float x = __uint_as_float((unsigned)pctx[o * CD + d] << 16);
    acc = fmaf(w, x, acc);
  }
  sacc[cg][d] = acc;
  if (d == 0) sl[cg] = L;
  __syncthreads();
  if (cg == 0) {
    const float A = sacc[0][d] + sacc[1][d] + sacc[2][d] + sacc[3][d];
    const float Lt = sl[0] + sl[1] + sl[2] + sl[3];
    const int tok = gpos[b * CG + g];
    ctx[((size_t)(bh * CS + tok)) * CD + d] = A / Lt;
  }
}

extern "C" void kernel_launch(void* const* d_in, const int* in_sizes, int n_in,
                              void* d_out, int out_size, void* d_ws, size_t ws_size,
                              hipStream_t stream) {
  const float* q = (const float*)d_in[0];
  const float* k = (const float*)d_in[1];
  const float* v = (const float*)d_in[2];
  const int* mask = (const int*)d_in[3];

  float* ctx = (float*)d_out;
  float* probs = ctx + (size_t)CBH * CS * CD;

  char* ws = (char*)d_ws;
  int* gpos = (int*)ws;                                  // 512 B
  int* gcount = (int*)(ws + 512);                        // 512 B
  float* pm = (float*)(ws + 1024);                       // CBH*NPART*CG f32
  float* pl = pm + (size_t)CBH * NPART * CG;             // CBH*NPART*CG f32
  unsigned short* pctx =
      (unsigned short*)(pl + (size_t)CBH * NPART * CG);  // CBH*NPART*CG*CD bf16

  k_main<<<dim3(NS1 + NS2, CBH), dim3(256), 0, stream>>>(
      q, k, v, mask, ctx, probs, pm, pl, pctx, gpos, gcount);
  k_combine<<<dim3(CG, CBH), dim3(256), 0, stream>>>(
      pm, pl, pctx, gpos, gcount, ctx);
}